// Round 2
// baseline (910.358 us; speedup 1.0000x reference)
//
#include <hip/hip_runtime.h>
#include <math.h>

#define NHEAD 16
#define SEQ   2048
#define DIM   128

// One wave (64 lanes) per (head, query-row). Flash-attention online softmax.
// Lane j of the wave scores key (j0+j); each lane owns 2 output dims (d=2*lane).
__global__ __launch_bounds__(256) void attn_blockcausal_fp32(
    const float* __restrict__ q,
    const float* __restrict__ k,
    const float* __restrict__ v,
    const int* __restrict__ offs, int n_off,
    float* __restrict__ out)
{
    __shared__ float qsm[4][DIM];
    const int lane  = threadIdx.x & 63;
    const int wslot = threadIdx.x >> 6;
    const int wid   = blockIdx.x * 4 + wslot;
    const int h     = wid / SEQ;
    const int qpos  = wid % SEQ;

    // stage this wave's q row into LDS (broadcast reads later)
    const float* qrow = q + ((size_t)h * SEQ + qpos) * DIM;
    ((float2*)qsm[wslot])[lane] = ((const float2*)qrow)[lane];
    __syncthreads();

    // doc start = largest offset <= qpos (offsets arrive as int32)
    int start = 0;
    for (int i = 0; i < n_off; ++i) {
        int o = offs[i];
        if (o <= qpos) start = o;
    }

    const float scale = 0.08838834764831843f; // 1/sqrt(128)

    const float* kh = k + (size_t)h * SEQ * DIM;
    const float* vh = v + (size_t)h * SEQ * DIM;

    float m = -INFINITY, l = 0.f, o0 = 0.f, o1 = 0.f;

    for (int j0 = start; j0 <= qpos; j0 += 64) {
        const int j = j0 + lane;
        float s = -INFINITY;
        if (j <= qpos) {
            const float4* kr = (const float4*)(kh + (size_t)j * DIM);
            const float4* qq = (const float4*)qsm[wslot];
            float acc = 0.f;
            #pragma unroll
            for (int d = 0; d < DIM / 4; ++d) {
                float4 a = kr[d];
                float4 b = qq[d];
                acc += a.x * b.x + a.y * b.y + a.z * b.z + a.w * b.w;
            }
            s = acc * scale;
        }

        // wave-wide max of this chunk
        float cm = s;
        #pragma unroll
        for (int off = 32; off >= 1; off >>= 1)
            cm = fmaxf(cm, __shfl_xor(cm, off));

        const float mn    = fmaxf(m, cm);
        const float alpha = (m == -INFINITY) ? 0.f : __expf(m - mn);
        const float p     = (s == -INFINITY) ? 0.f : __expf(s - mn);

        float ps = p;
        #pragma unroll
        for (int off = 32; off >= 1; off >>= 1)
            ps += __shfl_xor(ps, off);

        l  = l * alpha + ps;
        o0 *= alpha;
        o1 *= alpha;

        const int nj = min(64, qpos - j0 + 1); // wave-uniform trip count
        for (int jj = 0; jj < nj; ++jj) {
            const float pj = __shfl(p, jj);
            const float2 vv = *(const float2*)(vh + (size_t)(j0 + jj) * DIM + 2 * lane);
            o0 += pj * vv.x;
            o1 += pj * vv.y;
        }
        m = mn;
    }

    const float inv = 1.f / l;
    float2* orow = (float2*)(out + ((size_t)h * SEQ + qpos) * DIM);
    orow[lane] = make_float2(o0 * inv, o1 * inv);
}

extern "C" void kernel_launch(void* const* d_in, const int* in_sizes, int n_in,
                              void* d_out, int out_size, void* d_ws, size_t ws_size,
                              hipStream_t stream) {
    const float* q = (const float*)d_in[0];
    const float* k = (const float*)d_in[1];
    const float* v = (const float*)d_in[2];
    const int* offs = (const int*)d_in[3];
    const int n_off = in_sizes[3];
    float* out = (float*)d_out;

    const int waves  = NHEAD * SEQ;      // one wave per query row
    const int blocks = waves / 4;        // 4 waves per 256-thread block
    attn_blockcausal_fp32<<<blocks, 256, 0, stream>>>(q, k, v, offs, n_off, out);
}

// Round 3
// 56.301 us; speedup vs baseline: 16.1696x; 16.1696x over previous
//
#include <hip/hip_runtime.h>
#include <hip/hip_bf16.h>
#include <math.h>

#define NH 16
#define SL 2048
#define DM 128
#define KVB 64

typedef float f32x4 __attribute__((ext_vector_type(4)));
typedef short s16x8 __attribute__((ext_vector_type(8)));
typedef short s16x4 __attribute__((ext_vector_type(4)));

static __device__ __forceinline__ short f2bf(float f) {
  __hip_bfloat16 h = __float2bfloat16(f);
  return __builtin_bit_cast(short, h);
}

// Block: 128 q-rows (4 waves; wave w owns 16-row subtiles at q0+16w and q0+64+16w).
// KV tile 64. K staged row-major bf16 [64][128] XOR-swizzled; V staged transposed
// [128][64] XOR-swizzled. Swapped QK^T (mfma(K,Q) -> S^T, lane's q = lane&15).
// P relayout via per-wave swizzled LDS. fp32 accumulation, online softmax.
__global__ __launch_bounds__(256) void attn_mfma(
    const float* __restrict__ qg,
    const float* __restrict__ kg,
    const float* __restrict__ vg,
    const int* __restrict__ offs, int n_off,
    float* __restrict__ out)
{
  __shared__ __align__(16) char Kb[64 * 128 * 2];
  __shared__ __align__(16) char Vb[128 * 64 * 2];
  __shared__ __align__(16) char Pb[4][2][16 * 64 * 2];

  const int t    = threadIdx.x;
  const int lane = t & 63;
  const int w    = t >> 6;
  const int col  = lane & 15;
  const int g    = lane >> 4;

  const int h  = blockIdx.x >> 4;
  const int q0 = (blockIdx.x & 15) * 128;

  const float* qh = qg + (size_t)h * SL * DM;
  const float* kh = kg + (size_t)h * SL * DM;
  const float* vh = vg + (size_t)h * SL * DM;

  const float scale = 0.08838834764831843f; // 1/sqrt(128)

  // this wave's two 16-row q subtiles
  int qrow[2], qstart[2];
  qrow[0] = q0 + 16 * w + col;
  qrow[1] = q0 + 64 + 16 * w + col;
  #pragma unroll
  for (int s = 0; s < 2; ++s) {
    int st_ = 0;
    for (int i = 0; i < n_off; ++i) { int o = offs[i]; if (o <= qrow[s]) st_ = o; }
    qstart[s] = st_;
  }
  int kv_lo = 0;
  for (int i = 0; i < n_off; ++i) { int o = offs[i]; if (o <= q0) kv_lo = o; }

  // Q fragments, pre-scaled by 1/sqrt(D). A/B frag: lane holds [row=lane&15][k=8*(lane>>4)+j]
  s16x8 qf[2][4];
  #pragma unroll
  for (int s = 0; s < 2; ++s) {
    #pragma unroll
    for (int kk = 0; kk < 4; ++kk) {
      const float* qp = qh + (size_t)qrow[s] * DM + 32 * kk + 8 * g;
      f32x4 lo = *(const f32x4*)qp;
      f32x4 hi = *(const f32x4*)(qp + 4);
      s16x8 f;
      f[0] = f2bf(lo[0] * scale); f[1] = f2bf(lo[1] * scale);
      f[2] = f2bf(lo[2] * scale); f[3] = f2bf(lo[3] * scale);
      f[4] = f2bf(hi[0] * scale); f[5] = f2bf(hi[1] * scale);
      f[6] = f2bf(hi[2] * scale); f[7] = f2bf(hi[3] * scale);
      qf[s][kk] = f;
    }
  }

  f32x4 acc[2][8];
  #pragma unroll
  for (int s = 0; s < 2; ++s) {
    #pragma unroll
    for (int dt = 0; dt < 8; ++dt) { f32x4 z = {0.f, 0.f, 0.f, 0.f}; acc[s][dt] = z; }
  }
  float m_[2] = {-1e30f, -1e30f};
  float l_[2] = {0.f, 0.f};

  const int qmax0 = q0 + 16 * w + 15;
  const int qmax1 = q0 + 64 + 16 * w + 15;

  char* pb0 = &Pb[w][0][0];
  char* pb1 = &Pb[w][1][0];

  for (int kv0 = kv_lo; kv0 < q0 + 128; kv0 += KVB) {
    // ---- stage K (row-major) and V (transposed), fp32 -> bf16, swizzled ----
    {
      const float* ks = kh + (size_t)kv0 * DM;
      const float* vs = vh + (size_t)kv0 * DM;
      const int d0 = (t & 31) * 4;
      const int r0 = t >> 5;
      #pragma unroll
      for (int ri = 0; ri < 8; ++ri) {
        int r = r0 + 8 * ri;
        f32x4 f = *(const f32x4*)(ks + (size_t)r * DM + d0);
        s16x4 b;
        b[0] = f2bf(f[0]); b[1] = f2bf(f[1]); b[2] = f2bf(f[2]); b[3] = f2bf(f[3]);
        *(s16x4*)(Kb + ((r * 256 + d0 * 2) ^ ((r & 7) << 4))) = b;
      }
      #pragma unroll
      for (int ki = 0; ki < 2; ++ki) {
        int k0 = r0 * 4 + 32 * ki;
        f32x4 a0 = *(const f32x4*)(vs + (size_t)(k0 + 0) * DM + d0);
        f32x4 a1 = *(const f32x4*)(vs + (size_t)(k0 + 1) * DM + d0);
        f32x4 a2 = *(const f32x4*)(vs + (size_t)(k0 + 2) * DM + d0);
        f32x4 a3 = *(const f32x4*)(vs + (size_t)(k0 + 3) * DM + d0);
        #pragma unroll
        for (int dd = 0; dd < 4; ++dd) {
          int d = d0 + dd;
          s16x4 b;
          b[0] = f2bf(a0[dd]); b[1] = f2bf(a1[dd]); b[2] = f2bf(a2[dd]); b[3] = f2bf(a3[dd]);
          *(s16x4*)(Vb + ((d * 128 + k0 * 2) ^ ((d & 7) << 4))) = b;
        }
      }
    }
    __syncthreads();

    const bool act1 = (kv0 <= qmax1);
    const bool act0 = (kv0 <= qmax0);
    if (act1) {
      // ---- QK^T (swapped): st[s][kt] = K_tile_kt . Q_s^T -> S^T[k][q] ----
      f32x4 st[2][4];
      #pragma unroll
      for (int s = 0; s < 2; ++s) {
        #pragma unroll
        for (int kt = 0; kt < 4; ++kt) { f32x4 z = {0.f, 0.f, 0.f, 0.f}; st[s][kt] = z; }
      }
      #pragma unroll
      for (int kt = 0; kt < 4; ++kt) {
        int row = kt * 16 + col;
        #pragma unroll
        for (int kk = 0; kk < 4; ++kk) {
          s16x8 kf = *(const s16x8*)(Kb + ((row * 256 + 64 * kk + 16 * g) ^ ((row & 7) << 4)));
          if (act0) st[0][kt] = __builtin_amdgcn_mfma_f32_16x16x32_bf16(kf, qf[0][kk], st[0][kt], 0, 0, 0);
          st[1][kt] = __builtin_amdgcn_mfma_f32_16x16x32_bf16(kf, qf[1][kk], st[1][kt], 0, 0, 0);
        }
      }

      // ---- online softmax per subtile; write P (bf16) to per-wave LDS ----
      float alpha_s[2] = {1.f, 1.f};
      #pragma unroll
      for (int s = 0; s < 2; ++s) {
        if (s == 0 && !act0) continue;
        float cm = -3.0e38f;
        #pragma unroll
        for (int kt = 0; kt < 4; ++kt) {
          #pragma unroll
          for (int r = 0; r < 4; ++r) {
            int kpos = kv0 + kt * 16 + 4 * g + r;
            float x = st[s][kt][r];
            bool ok = (kpos <= qrow[s]) && (kpos >= qstart[s]);
            x = ok ? x : -3.0e38f;
            st[s][kt][r] = x;
            cm = fmaxf(cm, x);
          }
        }
        cm = fmaxf(cm, __shfl_xor(cm, 16));
        cm = fmaxf(cm, __shfl_xor(cm, 32));
        float mn = fmaxf(m_[s], cm);
        float al = __expf(m_[s] - mn);
        m_[s] = mn;
        float psum = 0.f;
        char* pb = (s == 0) ? pb0 : pb1;
        #pragma unroll
        for (int kt = 0; kt < 4; ++kt) {
          s16x4 pk;
          #pragma unroll
          for (int r = 0; r < 4; ++r) {
            float p = __expf(st[s][kt][r] - mn);
            psum += p;
            pk[r] = f2bf(p);
          }
          *(s16x4*)(pb + ((col * 128 + 32 * kt + 8 * g) ^ ((col & 7) << 4))) = pk;
        }
        psum += __shfl_xor(psum, 16);
        psum += __shfl_xor(psum, 32);
        l_[s] = l_[s] * al + psum;
        alpha_s[s] = al;
      }

      // ---- rescale O by alpha (per output row 4g+r) ----
      #pragma unroll
      for (int s = 0; s < 2; ++s) {
        if (s == 0 && !act0) continue;
        #pragma unroll
        for (int r = 0; r < 4; ++r) {
          float ar = __shfl(alpha_s[s], 4 * g + r);
          #pragma unroll
          for (int dt = 0; dt < 8; ++dt) acc[s][dt][r] *= ar;
        }
      }

      // cross-lane LDS RAW: drain P writes before fragment reads
      asm volatile("s_waitcnt lgkmcnt(0)" ::: "memory");
      __builtin_amdgcn_sched_barrier(0);

      // ---- PV: acc[s][dt] += P_s . V ----
      #pragma unroll
      for (int ksel = 0; ksel < 2; ++ksel) {
        s16x8 pa0, pa1;
        if (act0) pa0 = *(const s16x8*)(pb0 + ((col * 128 + 64 * ksel + 16 * g) ^ ((col & 7) << 4)));
        pa1 = *(const s16x8*)(pb1 + ((col * 128 + 64 * ksel + 16 * g) ^ ((col & 7) << 4)));
        #pragma unroll
        for (int dt = 0; dt < 8; ++dt) {
          int d = dt * 16 + col;
          s16x8 vf = *(const s16x8*)(Vb + ((d * 128 + 64 * ksel + 16 * g) ^ ((d & 7) << 4)));
          if (act0) acc[0][dt] = __builtin_amdgcn_mfma_f32_16x16x32_bf16(pa0, vf, acc[0][dt], 0, 0, 0);
          acc[1][dt] = __builtin_amdgcn_mfma_f32_16x16x32_bf16(pa1, vf, acc[1][dt], 0, 0, 0);
        }
      }
    }
    __syncthreads();
  }

  // ---- epilogue: divide by l, store fp32 ----
  #pragma unroll
  for (int s = 0; s < 2; ++s) {
    #pragma unroll
    for (int r = 0; r < 4; ++r) {
      float lr  = __shfl(l_[s], 4 * g + r);
      float inv = 1.f / lr;
      int row   = q0 + 16 * w + 64 * s + 4 * g + r;
      float* op = out + ((size_t)h * SL + row) * DM + col;
      #pragma unroll
      for (int dt = 0; dt < 8; ++dt) op[dt * 16] = acc[s][dt][r] * inv;
    }
  }
}

extern "C" void kernel_launch(void* const* d_in, const int* in_sizes, int n_in,
                              void* d_out, int out_size, void* d_ws, size_t ws_size,
                              hipStream_t stream) {
  const float* q = (const float*)d_in[0];
  const float* k = (const float*)d_in[1];
  const float* v = (const float*)d_in[2];
  const int* offs = (const int*)d_in[3];
  const int n_off = in_sizes[3];
  float* out = (float*)d_out;

  const int blocks = NH * (SL / 128); // 16 heads x 16 q-blocks = 256
  attn_mfma<<<blocks, 256, 0, stream>>>(q, k, v, offs, n_off, out);
}

// Round 4
// 31.336 us; speedup vs baseline: 29.0515x; 1.7967x over previous
//
#include <hip/hip_runtime.h>
#include <hip/hip_bf16.h>
#include <math.h>

#define NH 16
#define SL 2048
#define DM 128
#define KVB 64

typedef float f32x4 __attribute__((ext_vector_type(4)));
typedef short s16x8 __attribute__((ext_vector_type(8)));
typedef short s16x4 __attribute__((ext_vector_type(4)));

static __device__ __forceinline__ short f2bf(float f) {
  __hip_bfloat16 h = __float2bfloat16(f);
  return __builtin_bit_cast(short, h);
}

// Block: 64 q-rows, 4 waves, wave w owns rows [q0+16w, q0+16w+16). KV tile 64.
// K staged row-major bf16 [64][128] XOR-swizzled; V staged transposed [128][64]
// XOR-swizzled (rotated write order to spread banks). Swapped QK^T (mfma(K,Q)
// -> S^T, lane's q-row = lane&15). P relayout via per-wave swizzled LDS.
// fp32 accumulation, online softmax. Grid 512 = 2 blocks/CU.
__global__ __launch_bounds__(256) void attn_mfma(
    const float* __restrict__ qg,
    const float* __restrict__ kg,
    const float* __restrict__ vg,
    const int* __restrict__ offs, int n_off,
    float* __restrict__ out)
{
  __shared__ __align__(16) char Kb[64 * 128 * 2];
  __shared__ __align__(16) char Vb[128 * 64 * 2];
  __shared__ __align__(16) char Pb[4][16 * 64 * 2];

  const int t    = threadIdx.x;
  const int lane = t & 63;
  const int w    = t >> 6;
  const int col  = lane & 15;
  const int g    = lane >> 4;

  const int h  = blockIdx.x & 15;
  const int qb = 31 - (blockIdx.x >> 4);   // largest-work blocks first
  const int q0 = qb * 64;

  const float* qh = qg + (size_t)h * SL * DM;
  const float* kh = kg + (size_t)h * SL * DM;
  const float* vh = vg + (size_t)h * SL * DM;

  const float scale = 0.08838834764831843f; // 1/sqrt(128)

  const int qrow = q0 + 16 * w + col;
  int qstart = 0;
  for (int i = 0; i < n_off; ++i) { int o = offs[i]; if (o <= qrow) qstart = o; }
  int kv_lo = 0;
  for (int i = 0; i < n_off; ++i) { int o = offs[i]; if (o <= q0) kv_lo = o; }

  // Q fragment, pre-scaled. Layout: lane holds [row=lane&15][k=8*(lane>>4)+j]
  s16x8 qf[4];
  #pragma unroll
  for (int kk = 0; kk < 4; ++kk) {
    const float* qp = qh + (size_t)qrow * DM + 32 * kk + 8 * g;
    f32x4 lo = *(const f32x4*)qp;
    f32x4 hi = *(const f32x4*)(qp + 4);
    s16x8 f;
    f[0] = f2bf(lo[0] * scale); f[1] = f2bf(lo[1] * scale);
    f[2] = f2bf(lo[2] * scale); f[3] = f2bf(lo[3] * scale);
    f[4] = f2bf(hi[0] * scale); f[5] = f2bf(hi[1] * scale);
    f[6] = f2bf(hi[2] * scale); f[7] = f2bf(hi[3] * scale);
    qf[kk] = f;
  }

  f32x4 acc[8];
  #pragma unroll
  for (int dt = 0; dt < 8; ++dt) { f32x4 z = {0.f, 0.f, 0.f, 0.f}; acc[dt] = z; }
  float m_ = -1e30f, l_ = 0.f;

  char* pb = &Pb[w][0];

  for (int kv0 = kv_lo; kv0 < q0 + 64; kv0 += KVB) {
    // ---- stage K (row-major) and V (transposed), fp32 -> bf16, swizzled ----
    {
      const float* ks = kh + (size_t)kv0 * DM;
      const float* vs = vh + (size_t)kv0 * DM;
      const int d0 = (t & 31) * 4;
      const int r0 = t >> 5;
      #pragma unroll
      for (int ri = 0; ri < 8; ++ri) {
        int r = r0 + 8 * ri;
        f32x4 f = *(const f32x4*)(ks + (size_t)r * DM + d0);
        s16x4 b;
        b[0] = f2bf(f[0]); b[1] = f2bf(f[1]); b[2] = f2bf(f[2]); b[3] = f2bf(f[3]);
        *(s16x4*)(Kb + ((r * 256 + d0 * 2) ^ ((r & 7) << 4))) = b;
      }
      const int rot = (t >> 1) & 3;  // spread d&7 across XOR slots per write instr
      #pragma unroll
      for (int ki = 0; ki < 2; ++ki) {
        int k0 = r0 * 4 + 32 * ki;
        f32x4 a0 = *(const f32x4*)(vs + (size_t)(k0 + 0) * DM + d0);
        f32x4 a1 = *(const f32x4*)(vs + (size_t)(k0 + 1) * DM + d0);
        f32x4 a2 = *(const f32x4*)(vs + (size_t)(k0 + 2) * DM + d0);
        f32x4 a3 = *(const f32x4*)(vs + (size_t)(k0 + 3) * DM + d0);
        #pragma unroll
        for (int di = 0; di < 4; ++di) {
          int dd = (di + rot) & 3;
          int d = d0 + dd;
          s16x4 b;
          b[0] = f2bf(a0[dd]); b[1] = f2bf(a1[dd]); b[2] = f2bf(a2[dd]); b[3] = f2bf(a3[dd]);
          *(s16x4*)(Vb + ((d * 128 + k0 * 2) ^ ((d & 7) << 4))) = b;
        }
      }
    }
    __syncthreads();

    // ---- QK^T (swapped): st[kt] = K_tile_kt . Q^T -> S^T[k][q] ----
    f32x4 st[4];
    #pragma unroll
    for (int kt = 0; kt < 4; ++kt) { f32x4 z = {0.f, 0.f, 0.f, 0.f}; st[kt] = z; }
    __builtin_amdgcn_s_setprio(1);
    #pragma unroll
    for (int kt = 0; kt < 4; ++kt) {
      int row = kt * 16 + col;
      #pragma unroll
      for (int kk = 0; kk < 4; ++kk) {
        s16x8 kf = *(const s16x8*)(Kb + ((row * 256 + 64 * kk + 16 * g) ^ ((row & 7) << 4)));
        st[kt] = __builtin_amdgcn_mfma_f32_16x16x32_bf16(kf, qf[kk], st[kt], 0, 0, 0);
      }
    }
    __builtin_amdgcn_s_setprio(0);

    // ---- online softmax; write P (bf16) to per-wave LDS ----
    float cm = -3.0e38f;
    #pragma unroll
    for (int kt = 0; kt < 4; ++kt) {
      #pragma unroll
      for (int r = 0; r < 4; ++r) {
        int kpos = kv0 + kt * 16 + 4 * g + r;
        float x = st[kt][r];
        bool ok = (kpos <= qrow) && (kpos >= qstart);
        x = ok ? x : -3.0e38f;
        st[kt][r] = x;
        cm = fmaxf(cm, x);
      }
    }
    cm = fmaxf(cm, __shfl_xor(cm, 16));
    cm = fmaxf(cm, __shfl_xor(cm, 32));
    float mn = fmaxf(m_, cm);
    float al = __expf(m_ - mn);
    m_ = mn;
    float psum = 0.f;
    #pragma unroll
    for (int kt = 0; kt < 4; ++kt) {
      s16x4 pk;
      #pragma unroll
      for (int r = 0; r < 4; ++r) {
        float p = __expf(st[kt][r] - mn);
        psum += p;
        pk[r] = f2bf(p);
      }
      *(s16x4*)(pb + ((col * 128 + 32 * kt + 8 * g) ^ ((col & 7) << 4))) = pk;
    }
    psum += __shfl_xor(psum, 16);
    psum += __shfl_xor(psum, 32);
    l_ = l_ * al + psum;

    // ---- rescale O by alpha (per output row 4g+r) ----
    #pragma unroll
    for (int r = 0; r < 4; ++r) {
      float ar = __shfl(al, 4 * g + r);
      #pragma unroll
      for (int dt = 0; dt < 8; ++dt) acc[dt][r] *= ar;
    }

    // cross-lane LDS RAW: drain P writes before fragment reads
    asm volatile("s_waitcnt lgkmcnt(0)" ::: "memory");
    __builtin_amdgcn_sched_barrier(0);

    // ---- PV: acc[dt] += P . V ----
    __builtin_amdgcn_s_setprio(1);
    #pragma unroll
    for (int ksel = 0; ksel < 2; ++ksel) {
      s16x8 pa = *(const s16x8*)(pb + ((col * 128 + 64 * ksel + 16 * g) ^ ((col & 7) << 4)));
      #pragma unroll
      for (int dt = 0; dt < 8; ++dt) {
        int d = dt * 16 + col;
        s16x8 vf = *(const s16x8*)(Vb + ((d * 128 + 64 * ksel + 16 * g) ^ ((d & 7) << 4)));
        acc[dt] = __builtin_amdgcn_mfma_f32_16x16x32_bf16(pa, vf, acc[dt], 0, 0, 0);
      }
    }
    __builtin_amdgcn_s_setprio(0);
    __syncthreads();
  }

  // ---- epilogue: divide by l, store fp32 ----
  #pragma unroll
  for (int r = 0; r < 4; ++r) {
    float lr  = __shfl(l_, 4 * g + r);
    float inv = 1.f / lr;
    int row   = q0 + 16 * w + 4 * g + r;
    float* op = out + ((size_t)h * SL + row) * DM + col;
    #pragma unroll
    for (int dt = 0; dt < 8; ++dt) op[dt * 16] = acc[dt][r] * inv;
  }
}

extern "C" void kernel_launch(void* const* d_in, const int* in_sizes, int n_in,
                              void* d_out, int out_size, void* d_ws, size_t ws_size,
                              hipStream_t stream) {
  const float* q = (const float*)d_in[0];
  const float* k = (const float*)d_in[1];
  const float* v = (const float*)d_in[2];
  const int* offs = (const int*)d_in[3];
  const int n_off = in_sizes[3];
  float* out = (float*)d_out;

  const int blocks = NH * (SL / 64); // 16 heads x 32 q-blocks = 512
  attn_mfma<<<blocks, 256, 0, stream>>>(q, k, v, offs, n_off, out);
}